// Round 4
// baseline (195.686 us; speedup 1.0000x reference)
//
#include <hip/hip_runtime.h>

typedef __attribute__((ext_vector_type(8))) short bf16x8;
typedef __attribute__((ext_vector_type(16))) float f32x16;

__device__ __forceinline__ bool lex_lt(float av, int ai, float bv, int bi) {
  return av < bv || (av == bv && ai < bi);
}

// round-to-nearest-even fp32 -> bf16 (low 16 bits)
__device__ __forceinline__ unsigned bf16_rne(float v) {
  unsigned u = __float_as_uint(v);
  return (u + 0x7fffu + ((u >> 16) & 1u)) >> 16;
}

// packed RNE bf16 convert of (a,b) -> one 32-bit word (low=a, high=b)
__device__ __forceinline__ unsigned pk_bf16(float a, float b) {
  return bf16_rne(a) | (bf16_rne(b) << 16);
}

// Contention-free grid barrier (512 blocks, 512 threads/block).
// Arrival: one release store per block to its OWN slot (512 words = 32 lines
// -> no RMW serialization, no single-line hot spot).
// Departure: distributed poll -- thread t spins with RELAXED agent loads on
// slot t (no per-poll cache maintenance); closing __syncthreads() gates the
// block on all 512 slots. One __threadfence() = acquire for wtil/e2/wT reads.
// Bounded spin -> loud failure (wrong results), not a hang, if co-residency
// is ever violated.
__device__ __forceinline__ void grid_barrier(unsigned* bar) {
  __syncthreads();
  if (threadIdx.x == 0)
    __hip_atomic_store(&bar[blockIdx.x], 1u, __ATOMIC_RELEASE,
                       __HIP_MEMORY_SCOPE_AGENT);
  {
    long spins = 0;
    while (__hip_atomic_load(&bar[threadIdx.x], __ATOMIC_RELAXED,
                             __HIP_MEMORY_SCOPE_AGENT) == 0u) {
      __builtin_amdgcn_s_sleep(1);
      if (++spins > (1L << 20)) break;   // safety valve
    }
  }
  __threadfence();
  __syncthreads();
}

// ---------------------------------------------------------------------------
// vq_fused: ONE regular launch, 512 blocks (2/CU, co-resident), 512 threads.
// Phase A (pre): blocks 0..31 build k-major bf16-split codebook planes
//   wh[kg][n][8], wl[kg][n][8] + exact fp32 transposed codebook wT[n][d];
//   blocks 32..35 compute e2[k] in fp64. Issued FIRST so w loads fly early.
// Phase B: every block stages its own 64-position x tile into LDS.
// grid_barrier (replaces the old vq_pre kernel + 2 launch gaps)
// Phase C: unchanged K-loop (transposed MFMA), scan, merge, fp64 refine,
//   gather via transposed LDS bounce.
// ---------------------------------------------------------------------------
__global__ __launch_bounds__(512, 4) void vq_fused(
    const float* __restrict__ x, const float* __restrict__ w,
    float* __restrict__ e2g, short* __restrict__ wtil,
    float* __restrict__ wT, unsigned* __restrict__ bar,
    float* __restrict__ out, float* __restrict__ arg_out) {
  __shared__ __align__(16) char arena[76800];
  short* xh   = (short*)arena;                 // [64][256] swizzled, 32 KB
  short* xl   = (short*)(arena + 32768);       // 32 KB
  float* e2s  = (float*)(arena + 65536);       // 2 KB
  float* tv1  = (float*)(arena + 67584);       // [8][64]
  float* tv2  = (float*)(arena + 69632);
  int*   ti1  = (int*)(arena + 71680);
  int*   ti2  = (int*)(arena + 73728);
  int*   p1S  = (int*)(arena + 75776);         // [64]
  int*   p2S  = (int*)(arena + 76032);
  int*   needS= (int*)(arena + 76288);
  int*   rpickS=(int*)(arena + 76544);
  // gather phase: gbuf[d*68 + pos], 256x68 floats = 69632 B
  // (aliases xh/xl/e2s/tv which are dead; p1S..rpickS at >=75776 survive)
  float* gbuf = (float*)arena;

  const int tid = threadIdx.x;
  const int bid = blockIdx.x;

  // ---- Phase A: codebook pre-processing, spread over blocks 0..35
  if (bid < 32) {
    int gid = bid * 512 + tid;  // 0..16383
    int n  = gid & 511;
    int kg = gid >> 9;
    bf16x8 hv, lv;
    float vv[8];
#pragma unroll
    for (int j = 0; j < 8; ++j) {
      float v = w[(kg * 8 + j) * 512 + n];
      vv[j] = v;
      unsigned h = bf16_rne(v);
      float hf = __uint_as_float(h << 16);
      unsigned l = bf16_rne(v - hf);
      hv[j] = (short)h;
      lv[j] = (short)l;
    }
    short* dst = wtil + (size_t)gid * 8;   // (kg*512 + n)*8
    *(bf16x8*)dst = hv;
    *(bf16x8*)(dst + 131072) = lv;
    if (wT) {
      float* p = wT + (size_t)n * 256 + kg * 8;
      *(float4*)p       = make_float4(vv[0], vv[1], vv[2], vv[3]);
      *(float4*)(p + 4) = make_float4(vv[4], vv[5], vv[6], vv[7]);
    }
  } else if (bid < 36) {
    int t = (bid - 32) * 512 + tid;  // 0..2047
    int k = t >> 2;
    int part = t & 3;
    double s = 0.0;
#pragma unroll 8
    for (int d = part * 64; d < part * 64 + 64; ++d) {
      double v = (double)w[d * 512 + k];
      s = fma(v, v, s);
    }
    s += __shfl_xor(s, 1);
    s += __shfl_xor(s, 2);
    if (part == 0) e2g[k] = (float)s;
  }

  const int b  = bid >> 4;
  const int n0 = (bid & 15) << 6;              // 64 positions
  const float* xbase = x + (size_t)b * 262144 + n0;

  // ---- Phase B: stage all 256 dims of own x tile in one pass
  {
    const int n4  = tid & 15;      // position-group (4 pos each)
    const int kgp = tid >> 4;      // 0..31: all kg groups
    float4 v[8];
#pragma unroll
    for (int j = 0; j < 8; ++j)
      v[j] = *(const float4*)(xbase + (size_t)(kgp * 8 + j) * 1024 + (n4 << 2));
#pragma unroll
    for (int i = 0; i < 4; ++i) {
      int m = (n4 << 2) + i;
      union { int w4[4]; bf16x8 v8; } H, L;
#pragma unroll
      for (int jj = 0; jj < 4; ++jj) {
        float a = (i == 0) ? v[2*jj].x : (i == 1) ? v[2*jj].y : (i == 2) ? v[2*jj].z : v[2*jj].w;
        float c = (i == 0) ? v[2*jj+1].x : (i == 1) ? v[2*jj+1].y : (i == 2) ? v[2*jj+1].z : v[2*jj+1].w;
        unsigned hu = pk_bf16(a, c);
        float haf = __uint_as_float(hu << 16);
        float hcf = __uint_as_float(hu & 0xffff0000u);
        unsigned lu = pk_bf16(a - haf, c - hcf);
        H.w4[jj] = (int)hu;
        L.w4[jj] = (int)lu;
      }
      int off = (m << 8) + ((kgp ^ (m & 7)) << 3);
      *(bf16x8*)&xh[off] = H.v8;
      *(bf16x8*)&xl[off] = L.v8;
    }
  }

  // ---- grid-wide sync: wtil/e2/wT now visible; own LDS tile staged
  grid_barrier(bar);

  const int lane = tid & 63;
  const int wv   = tid >> 6;     // wave 0..7: codes [wv*64, wv*64+64)
  const int ln   = lane & 31;
  const int half = lane >> 5;
  const int wb   = wv << 6;

  f32x16 acc[2][2];   // [code-tile ct][pos-tile pt]
#pragma unroll
  for (int ct = 0; ct < 2; ++ct)
#pragma unroll
    for (int pt = 0; pt < 2; ++pt)
#pragma unroll
      for (int r = 0; r < 16; ++r) acc[ct][pt][r] = 0.f;

  const int asw = ln & 7;
  const int abase = ln << 8;

  int bofs[2];
#pragma unroll
  for (int ct = 0; ct < 2; ++ct) bofs[ct] = (wb + (ct << 5) + ln) << 3;

  bf16x8 pch[2], pcl[2];
#pragma unroll
  for (int ct = 0; ct < 2; ++ct) {
    const short* p = wtil + (half << 12) + bofs[ct];
    pch[ct] = *(const bf16x8*)p;
    pcl[ct] = *(const bf16x8*)(p + 131072);
  }

  auto kstep = [&](int ch) {
    const int kg = (ch << 1) + half;
    const int ao = abase + ((kg ^ asw) << 3);
    bf16x8 xf[2], xg[2];
#pragma unroll
    for (int pt = 0; pt < 2; ++pt) {
      xf[pt] = *(const bf16x8*)&xh[ao + (pt << 13)];
      xg[pt] = *(const bf16x8*)&xl[ao + (pt << 13)];
    }
    bf16x8 cfh[2], cfl[2];
#pragma unroll
    for (int ct = 0; ct < 2; ++ct) { cfh[ct] = pch[ct]; cfl[ct] = pcl[ct]; }
    if (ch < 15) {
      const int kgn = ((ch + 1) << 1) + half;
#pragma unroll
      for (int ct = 0; ct < 2; ++ct) {
        const short* p = wtil + (kgn << 12) + bofs[ct];
        pch[ct] = *(const bf16x8*)p;
        pcl[ct] = *(const bf16x8*)(p + 131072);
      }
    }
#pragma unroll
    for (int ct = 0; ct < 2; ++ct)
#pragma unroll
      for (int pt = 0; pt < 2; ++pt) {
        acc[ct][pt] = __builtin_amdgcn_mfma_f32_32x32x16_bf16(cfh[ct], xf[pt], acc[ct][pt], 0, 0, 0);
        acc[ct][pt] = __builtin_amdgcn_mfma_f32_32x32x16_bf16(cfh[ct], xg[pt], acc[ct][pt], 0, 0, 0);
        acc[ct][pt] = __builtin_amdgcn_mfma_f32_32x32x16_bf16(cfl[ct], xf[pt], acc[ct][pt], 0, 0, 0);
      }
  };

  kstep(0);  kstep(1);  kstep(2);  kstep(3);
  kstep(4);  kstep(5);  kstep(6);  kstep(7);
  kstep(8);  kstep(9);  kstep(10); kstep(11);
  kstep(12); kstep(13); kstep(14); kstep(15);

  // ---- e2 to LDS (e2g valid since barrier; L2-warm now)
  e2s[tid] = e2g[tid];
  __syncthreads();

  // ---- epilogue: per-lane register scan (codes in regs), one xor-32 merge
  float e2r[2][16];
#pragma unroll
  for (int ct = 0; ct < 2; ++ct)
#pragma unroll
    for (int r = 0; r < 16; ++r)
      e2r[ct][r] = e2s[wb + (ct << 5) + (r & 3) + ((r >> 2) << 3) + (half << 2)];

#pragma unroll
  for (int pt = 0; pt < 2; ++pt) {
    float v1 = 3.4e38f, v2 = 3.4e38f;
    int i1 = 0x7fffffff, i2 = 0x7fffffff;
#pragma unroll
    for (int ct = 0; ct < 2; ++ct) {
#pragma unroll
      for (int r = 0; r < 16; ++r) {
        int k = wb + (ct << 5) + (r & 3) + ((r >> 2) << 3) + (half << 2);
        float s = fmaf(-2.f, acc[ct][pt][r], e2r[ct][r]);
        if (lex_lt(s, k, v1, i1)) { v2 = v1; i2 = i1; v1 = s; i1 = k; }
        else if (lex_lt(s, k, v2, i2)) { v2 = s; i2 = k; }
      }
    }
    {
      float ov1 = __shfl_xor(v1, 32);
      int   oi1 = __shfl_xor(i1, 32);
      float ov2 = __shfl_xor(v2, 32);
      int   oi2 = __shfl_xor(i2, 32);
      bool aFirst = lex_lt(v1, i1, ov1, oi1);
      float nv1 = aFirst ? v1 : ov1;  int ni1 = aFirst ? i1 : oi1;
      float cv  = aFirst ? ov1 : v1;  int ci  = aFirst ? oi1 : i1;
      float sv  = aFirst ? v2 : ov2;  int si  = aFirst ? i2 : oi2;
      bool cFirst = lex_lt(cv, ci, sv, si);
      v1 = nv1; i1 = ni1;
      v2 = cFirst ? cv : sv; i2 = cFirst ? ci : si;
    }
    if (half == 0) {
      int s = (wv << 6) + (pt << 5) + ln;
      tv1[s] = v1; ti1[s] = i1; tv2[s] = v2; ti2[s] = i2;
    }
  }
  __syncthreads();

  // ---- cross-wave merge (tid<64), publish top-2 + need flag
  if (tid < 64) {
    int row = tid;
    float v1 = 3.4e38f, v2 = 3.4e38f;
    int i1 = 0x7fffffff, i2 = 0x7fffffff;
#pragma unroll
    for (int wvv = 0; wvv < 8; ++wvv) {
      int s = (wvv << 6) + row;
      float a1 = tv1[s]; int ai = ti1[s];
      float a2 = tv2[s]; int bi = ti2[s];
      if (lex_lt(a1, ai, v1, i1)) { v2 = v1; i2 = i1; v1 = a1; i1 = ai; }
      else if (lex_lt(a1, ai, v2, i2)) { v2 = a1; i2 = ai; }
      if (lex_lt(a2, bi, v1, i1)) { v2 = v1; i2 = i1; v1 = a2; i1 = bi; }
      else if (lex_lt(a2, bi, v2, i2)) { v2 = a2; i2 = bi; }
    }
    p1S[row] = i1; p2S[row] = i2;
    needS[row] = (v2 - v1 < 0.01f) ? 1 : 0;   // >3x worst-case split-GEMM jitter
    rpickS[row] = i1;
  }
  __syncthreads();

  // ---- parallel fp64 refinement: wave wv handles rows wv, wv+8, ...
  for (int t = 0; t < 8; ++t) {
    int row = (t << 3) + wv;
    if (needS[row]) {
      int i1 = p1S[row], i2 = p2S[row];
      const float* xp = x + (size_t)b * 262144 + n0 + row;
      double s1 = 0.0, s2 = 0.0;
      int k0 = lane << 2;
#pragma unroll
      for (int i = 0; i < 4; ++i) {
        int k = k0 + i;
        double xv = (double)xp[(size_t)k * 1024];
        double w1 = (double)w[k * 512 + i1];
        double w2 = (double)w[k * 512 + i2];
        double t1 = xv - w1, t2 = xv - w2;
        s1 = fma(t1, t1, s1);
        s2 = fma(t2, t2, s2);
      }
#pragma unroll
      for (int off = 32; off >= 1; off >>= 1) {
        s1 += __shfl_xor(s1, off);
        s2 += __shfl_xor(s2, off);
      }
      if (lane == 0 && (s2 < s1 || (s2 == s1 && i2 < i1))) rpickS[row] = i2;
    }
  }
  __syncthreads();

  // ---- write argmin + gather via transposed LDS bounce
  if (tid < 64) arg_out[b * 1024 + n0 + tid] = (float)rpickS[tid];

  if (wT) {
    {
      const int pos  = tid >> 3;        // 64 positions, 8 threads each
      const int dseg = tid & 7;
      const float* wrow = wT + (size_t)rpickS[pos] * 256;
#pragma unroll
      for (int j = 0; j < 8; ++j) {
        int d0 = (j << 5) + (dseg << 2);
        float4 v = *(const float4*)(wrow + d0);
        gbuf[(d0 + 0) * 68 + pos] = v.x;
        gbuf[(d0 + 1) * 68 + pos] = v.y;
        gbuf[(d0 + 2) * 68 + pos] = v.z;
        gbuf[(d0 + 3) * 68 + pos] = v.w;
      }
    }
    __syncthreads();
    {
      const int nn0 = (tid & 15) << 2;
      const int d0g = tid >> 4;          // 0..31
      float* obase = out + (size_t)b * 262144 + n0 + nn0;
#pragma unroll
      for (int dg = 0; dg < 8; ++dg) {
        int d = d0g + (dg << 5);
        float4 o = *(const float4*)&gbuf[d * 68 + nn0];
        *(float4*)(obase + (size_t)d * 1024) = o;
      }
    }
  } else {
    const int nn0 = (tid & 15) << 2;
    const int d0g = tid >> 4;
    int pk0 = rpickS[nn0], pk1 = rpickS[nn0 + 1], pk2 = rpickS[nn0 + 2], pk3 = rpickS[nn0 + 3];
    float* obase = out + (size_t)b * 262144 + n0 + nn0;
#pragma unroll
    for (int dg = 0; dg < 8; ++dg) {
      int d = d0g + (dg << 5);
      const float* wr = w + d * 512;
      float4 o = make_float4(wr[pk0], wr[pk1], wr[pk2], wr[pk3]);
      *(float4*)(obase + (size_t)d * 1024) = o;
    }
  }
}

// ---------------------------------------------------------------------------
extern "C" void kernel_launch(void* const* d_in, const int* in_sizes, int n_in,
                              void* d_out, int out_size, void* d_ws, size_t ws_size,
                              hipStream_t stream) {
  const float* x = (const float*)d_in[0];
  const float* w = (const float*)d_in[1];
  float* out  = (float*)d_out;
  float* argf = out + 8388608;
  float* e2   = (float*)d_ws;                       // 2048 B
  short* wtil = (short*)((char*)d_ws + 2048);       // 512 KB
  size_t need = 2048 + 524288 + 524288 + (1 << 21) + 2048;
  float* wT   = (ws_size >= need) ? (float*)((char*)d_ws + 2048 + 524288) : nullptr;
  unsigned* bar = (unsigned*)((char*)d_ws + (1 << 21));  // 512 slots, 2 KB

  hipMemsetAsync(bar, 0, 2048, stream);   // workspace is poisoned each iter
  vq_fused<<<512, 512, 0, stream>>>(x, w, e2, wtil, wT, bar, out, argf);
}

// Round 5
// 121.188 us; speedup vs baseline: 1.6147x; 1.6147x over previous
//
#include <hip/hip_runtime.h>

typedef __attribute__((ext_vector_type(8))) short bf16x8;
typedef __attribute__((ext_vector_type(16))) float f32x16;

__device__ __forceinline__ bool lex_lt(float av, int ai, float bv, int bi) {
  return av < bv || (av == bv && ai < bi);
}

// round-to-nearest-even fp32 -> bf16 (low 16 bits)
__device__ __forceinline__ unsigned bf16_rne(float v) {
  unsigned u = __float_as_uint(v);
  return (u + 0x7fffu + ((u >> 16) & 1u)) >> 16;
}

// packed RNE bf16 convert of (a,b) -> one 32-bit word (low=a, high=b)
__device__ __forceinline__ unsigned pk_bf16(float a, float b) {
  return bf16_rne(a) | (bf16_rne(b) << 16);
}

// ---------------------------------------------------------------------------
// vq_pre: blocks 0..63 build k-major bf16-split codebook planes
// wh[kg][n][8], wl[kg][n][8] + exact fp32 transposed codebook wT[n][d];
// blocks 64..71: e2[k] in fp64 (4-way d-split per k).
// ---------------------------------------------------------------------------
__global__ __launch_bounds__(256) void vq_pre(
    const float* __restrict__ w, float* __restrict__ e2,
    short* __restrict__ wtil, float* __restrict__ wT) {
  int blk = blockIdx.x;
  if (blk < 64) {
    int gid = blk * 256 + threadIdx.x;  // 16384 threads
    int n  = gid & 511;
    int kg = gid >> 9;
    bf16x8 hv, lv;
    float vv[8];
#pragma unroll
    for (int j = 0; j < 8; ++j) {
      float v = w[(kg * 8 + j) * 512 + n];
      vv[j] = v;
      unsigned h = bf16_rne(v);
      float hf = __uint_as_float(h << 16);
      unsigned l = bf16_rne(v - hf);
      hv[j] = (short)h;
      lv[j] = (short)l;
    }
    short* dst = wtil + (size_t)gid * 8;   // (kg*512 + n)*8
    *(bf16x8*)dst = hv;
    *(bf16x8*)(dst + 131072) = lv;
    if (wT) {
      float* p = wT + (size_t)n * 256 + kg * 8;
      *(float4*)p       = make_float4(vv[0], vv[1], vv[2], vv[3]);
      *(float4*)(p + 4) = make_float4(vv[4], vv[5], vv[6], vv[7]);
    }
  } else {
    int t = (blk - 64) * 256 + threadIdx.x;  // 0..2047
    int k = t >> 2;
    int part = t & 3;
    double s = 0.0;
#pragma unroll 8
    for (int d = part * 64; d < part * 64 + 64; ++d) {
      double v = (double)w[d * 512 + k];
      s = fma(v, v, s);
    }
    s += __shfl_xor(s, 1);
    s += __shfl_xor(s, 2);
    if (part == 0) e2[k] = (float)s;
  }
}

// ---------------------------------------------------------------------------
// vq_main: 1024 blocks (4/CU via 38.5 KB LDS + <=64 regs), 512 threads.
// Block = 32 positions x 512 codes. Register-lean K-loop (acc[2] = 32 regs,
// no code prefetch double-buffer, e2 read from LDS broadcast in scan) so the
// allocator fits the 64-reg bucket -> 8 waves/SIMD.
// ---------------------------------------------------------------------------
__global__ __launch_bounds__(512, 8) void vq_main(
    const float* __restrict__ x, const float* __restrict__ w,
    const float* __restrict__ e2g, const short* __restrict__ wtil,
    const float* __restrict__ wT,
    float* __restrict__ out, float* __restrict__ arg_out) {
  __shared__ __align__(16) char arena[39424];
  short* xh   = (short*)arena;                 // [32][256] swizzled, 16 KB
  short* xl   = (short*)(arena + 16384);       // 16 KB
  float* e2s  = (float*)(arena + 32768);       // 2 KB
  float* tv1  = (float*)(arena + 34816);       // [8][32]
  float* tv2  = (float*)(arena + 35840);
  int*   ti1  = (int*)(arena + 36864);
  int*   ti2  = (int*)(arena + 37888);
  int*   p1S  = (int*)(arena + 38912);         // [32]
  int*   p2S  = (int*)(arena + 39040);
  int*   needS= (int*)(arena + 39168);
  int*   rpickS=(int*)(arena + 39296);
  // gather phase: gbuf[d*36 + pos], 256x36 floats = 36864 B
  // (aliases xh/xl/e2s/tv/ti which are dead; p1S..rpickS at >=38912 survive)
  float* gbuf = (float*)arena;

  const int tid = threadIdx.x;
  const int b  = blockIdx.x >> 5;
  const int n0 = (blockIdx.x & 31) << 5;       // 32 positions
  const float* xbase = x + (size_t)b * 262144 + n0;

  // ---- stage all 256 dims in one pass (2 positions x 1 kg per thread)
  {
    e2s[tid] = e2g[tid];
    const int n2  = tid & 15;      // position-pair index (2 pos each)
    const int kgp = tid >> 4;      // 0..31: all kg groups
    float2 v[8];
#pragma unroll
    for (int j = 0; j < 8; ++j)
      v[j] = *(const float2*)(xbase + (size_t)(kgp * 8 + j) * 1024 + (n2 << 1));
#pragma unroll
    for (int i = 0; i < 2; ++i) {
      int m = (n2 << 1) + i;
      union { int w4[4]; bf16x8 v8; } H, L;
#pragma unroll
      for (int jj = 0; jj < 4; ++jj) {
        float a = (i == 0) ? v[2*jj].x   : v[2*jj].y;
        float c = (i == 0) ? v[2*jj+1].x : v[2*jj+1].y;
        unsigned hu = pk_bf16(a, c);
        float haf = __uint_as_float(hu << 16);
        float hcf = __uint_as_float(hu & 0xffff0000u);
        unsigned lu = pk_bf16(a - haf, c - hcf);
        H.w4[jj] = (int)hu;
        L.w4[jj] = (int)lu;
      }
      int off = (m << 8) + ((kgp ^ (m & 7)) << 3);
      *(bf16x8*)&xh[off] = H.v8;
      *(bf16x8*)&xl[off] = L.v8;
    }
  }
  __syncthreads();

  const int lane = tid & 63;
  const int wv   = tid >> 6;     // wave 0..7: codes [wv*64, wv*64+64)
  const int ln   = lane & 31;
  const int half = lane >> 5;
  const int wb   = wv << 6;

  f32x16 acc[2];   // [code-tile ct]; 32 positions -> single pos tile
#pragma unroll
  for (int ct = 0; ct < 2; ++ct)
#pragma unroll
    for (int r = 0; r < 16; ++r) acc[ct][r] = 0.f;

  const int asw = ln & 7;
  const int abase = ln << 8;

  int bofs[2];
#pragma unroll
  for (int ct = 0; ct < 2; ++ct) bofs[ct] = (wb + (ct << 5) + ln) << 3;

  auto kstep = [&](int ch) {
    const int kg = (ch << 1) + half;
    const int ao = abase + ((kg ^ asw) << 3);
    bf16x8 xf = *(const bf16x8*)&xh[ao];
    bf16x8 xg = *(const bf16x8*)&xl[ao];
    const short* p0 = wtil + (kg << 12) + bofs[0];
    const short* p1 = wtil + (kg << 12) + bofs[1];
    bf16x8 ch0 = *(const bf16x8*)p0;
    bf16x8 cl0 = *(const bf16x8*)(p0 + 131072);
    bf16x8 ch1 = *(const bf16x8*)p1;
    bf16x8 cl1 = *(const bf16x8*)(p1 + 131072);
    acc[0] = __builtin_amdgcn_mfma_f32_32x32x16_bf16(ch0, xf, acc[0], 0, 0, 0);
    acc[0] = __builtin_amdgcn_mfma_f32_32x32x16_bf16(ch0, xg, acc[0], 0, 0, 0);
    acc[0] = __builtin_amdgcn_mfma_f32_32x32x16_bf16(cl0, xf, acc[0], 0, 0, 0);
    acc[1] = __builtin_amdgcn_mfma_f32_32x32x16_bf16(ch1, xf, acc[1], 0, 0, 0);
    acc[1] = __builtin_amdgcn_mfma_f32_32x32x16_bf16(ch1, xg, acc[1], 0, 0, 0);
    acc[1] = __builtin_amdgcn_mfma_f32_32x32x16_bf16(cl1, xf, acc[1], 0, 0, 0);
  };

  kstep(0);  kstep(1);  kstep(2);  kstep(3);
  kstep(4);  kstep(5);  kstep(6);  kstep(7);
  kstep(8);  kstep(9);  kstep(10); kstep(11);
  kstep(12); kstep(13); kstep(14); kstep(15);

  // ---- epilogue: per-lane register scan; e2 via LDS broadcast (uniform in ln)
  {
    float v1 = 3.4e38f, v2 = 3.4e38f;
    int i1 = 0x7fffffff, i2 = 0x7fffffff;
#pragma unroll
    for (int ct = 0; ct < 2; ++ct) {
#pragma unroll
      for (int r = 0; r < 16; ++r) {
        int k = wb + (ct << 5) + (r & 3) + ((r >> 2) << 3) + (half << 2);
        float s = fmaf(-2.f, acc[ct][r], e2s[k]);
        if (lex_lt(s, k, v1, i1)) { v2 = v1; i2 = i1; v1 = s; i1 = k; }
        else if (lex_lt(s, k, v2, i2)) { v2 = s; i2 = k; }
      }
    }
    {
      float ov1 = __shfl_xor(v1, 32);
      int   oi1 = __shfl_xor(i1, 32);
      float ov2 = __shfl_xor(v2, 32);
      int   oi2 = __shfl_xor(i2, 32);
      bool aFirst = lex_lt(v1, i1, ov1, oi1);
      float nv1 = aFirst ? v1 : ov1;  int ni1 = aFirst ? i1 : oi1;
      float cv  = aFirst ? ov1 : v1;  int ci  = aFirst ? oi1 : i1;
      float sv  = aFirst ? v2 : ov2;  int si  = aFirst ? i2 : oi2;
      bool cFirst = lex_lt(cv, ci, sv, si);
      v1 = nv1; i1 = ni1;
      v2 = cFirst ? cv : sv; i2 = cFirst ? ci : si;
    }
    if (half == 0) {
      int s = (wv << 5) + ln;
      tv1[s] = v1; ti1[s] = i1; tv2[s] = v2; ti2[s] = i2;
    }
  }
  __syncthreads();

  // ---- cross-wave merge (tid<32), publish top-2 + need flag
  if (tid < 32) {
    int row = tid;
    float v1 = 3.4e38f, v2 = 3.4e38f;
    int i1 = 0x7fffffff, i2 = 0x7fffffff;
#pragma unroll
    for (int wvv = 0; wvv < 8; ++wvv) {
      int s = (wvv << 5) + row;
      float a1 = tv1[s]; int ai = ti1[s];
      float a2 = tv2[s]; int bi = ti2[s];
      if (lex_lt(a1, ai, v1, i1)) { v2 = v1; i2 = i1; v1 = a1; i1 = ai; }
      else if (lex_lt(a1, ai, v2, i2)) { v2 = a1; i2 = ai; }
      if (lex_lt(a2, bi, v1, i1)) { v2 = v1; i2 = i1; v1 = a2; i1 = bi; }
      else if (lex_lt(a2, bi, v2, i2)) { v2 = a2; i2 = bi; }
    }
    p1S[row] = i1; p2S[row] = i2;
    needS[row] = (v2 - v1 < 0.01f) ? 1 : 0;   // >3x worst-case split-GEMM jitter
    rpickS[row] = i1;
  }
  __syncthreads();

  // ---- parallel fp64 refinement: wave wv handles rows wv, wv+8, ...
  for (int t = 0; t < 4; ++t) {
    int row = (t << 3) + wv;
    if (needS[row]) {
      int i1 = p1S[row], i2 = p2S[row];
      const float* xp = x + (size_t)b * 262144 + n0 + row;
      double s1 = 0.0, s2 = 0.0;
      int k0 = lane << 2;
#pragma unroll
      for (int i = 0; i < 4; ++i) {
        int k = k0 + i;
        double xv = (double)xp[(size_t)k * 1024];
        double w1 = (double)w[k * 512 + i1];
        double w2 = (double)w[k * 512 + i2];
        double t1 = xv - w1, t2 = xv - w2;
        s1 = fma(t1, t1, s1);
        s2 = fma(t2, t2, s2);
      }
#pragma unroll
      for (int off = 32; off >= 1; off >>= 1) {
        s1 += __shfl_xor(s1, off);
        s2 += __shfl_xor(s2, off);
      }
      if (lane == 0 && (s2 < s1 || (s2 == s1 && i2 < i1))) rpickS[row] = i2;
    }
  }
  __syncthreads();

  // ---- write argmin + gather via transposed LDS bounce
  if (tid < 32) arg_out[b * 1024 + n0 + tid] = (float)rpickS[tid];

  if (wT) {
    {
      const int pos  = tid >> 4;        // 32 positions, 16 threads each
      const int dseg = tid & 15;
      const float* wrow = wT + (size_t)rpickS[pos] * 256;
#pragma unroll
      for (int j = 0; j < 4; ++j) {
        int d0 = (j << 6) + (dseg << 2);
        float4 v = *(const float4*)(wrow + d0);
        gbuf[(d0 + 0) * 36 + pos] = v.x;
        gbuf[(d0 + 1) * 36 + pos] = v.y;
        gbuf[(d0 + 2) * 36 + pos] = v.z;
        gbuf[(d0 + 3) * 36 + pos] = v.w;
      }
    }
    __syncthreads();
    {
      const int nn0 = (tid & 7) << 2;
      const int d0g = tid >> 3;          // 0..63
      float* obase = out + (size_t)b * 262144 + n0 + nn0;
#pragma unroll
      for (int dg = 0; dg < 4; ++dg) {
        int d = d0g + (dg << 6);
        float4 o = *(const float4*)&gbuf[d * 36 + nn0];
        *(float4*)(obase + (size_t)d * 1024) = o;
      }
    }
  } else {
    const int nn0 = (tid & 7) << 2;
    const int d0g = tid >> 3;
    int pk0 = rpickS[nn0], pk1 = rpickS[nn0 + 1], pk2 = rpickS[nn0 + 2], pk3 = rpickS[nn0 + 3];
    float* obase = out + (size_t)b * 262144 + n0 + nn0;
#pragma unroll
    for (int dg = 0; dg < 4; ++dg) {
      int d = d0g + (dg << 6);
      const float* wr = w + d * 512;
      float4 o = make_float4(wr[pk0], wr[pk1], wr[pk2], wr[pk3]);
      *(float4*)(obase + (size_t)d * 1024) = o;
    }
  }
}

// ---------------------------------------------------------------------------
extern "C" void kernel_launch(void* const* d_in, const int* in_sizes, int n_in,
                              void* d_out, int out_size, void* d_ws, size_t ws_size,
                              hipStream_t stream) {
  const float* x = (const float*)d_in[0];
  const float* w = (const float*)d_in[1];
  float* out  = (float*)d_out;
  float* argf = out + 8388608;
  float* e2   = (float*)d_ws;                       // 2048 B
  short* wtil = (short*)((char*)d_ws + 2048);       // 512 KB
  size_t need = 2048 + 524288 + 524288;
  float* wT   = (ws_size >= need) ? (float*)((char*)d_ws + 2048 + 524288) : nullptr;

  vq_pre<<<72, 256, 0, stream>>>(w, e2, wtil, wT);
  vq_main<<<1024, 512, 0, stream>>>(x, w, e2, wtil, wT, out, argf);
}

// Round 6
// 119.928 us; speedup vs baseline: 1.6317x; 1.0105x over previous
//
#include <hip/hip_runtime.h>

typedef __attribute__((ext_vector_type(8))) short bf16x8;
typedef __attribute__((ext_vector_type(16))) float f32x16;

__device__ __forceinline__ bool lex_lt(float av, int ai, float bv, int bi) {
  return av < bv || (av == bv && ai < bi);
}

// round-to-nearest-even fp32 -> bf16 (low 16 bits)
__device__ __forceinline__ unsigned bf16_rne(float v) {
  unsigned u = __float_as_uint(v);
  return (u + 0x7fffu + ((u >> 16) & 1u)) >> 16;
}

// packed RNE bf16 convert of (a,b) -> one 32-bit word (low=a, high=b)
__device__ __forceinline__ unsigned pk_bf16(float a, float b) {
  return bf16_rne(a) | (bf16_rne(b) << 16);
}

// ---------------------------------------------------------------------------
// vq_pre: blocks 0..63 build k-major bf16-split codebook planes
// wh[kg][n][8], wl[kg][n][8] + exact fp32 transposed codebook wT[n][d];
// blocks 64..71: e2[k] in fp64 (4-way d-split per k).
// ---------------------------------------------------------------------------
__global__ __launch_bounds__(256) void vq_pre(
    const float* __restrict__ w, float* __restrict__ e2,
    short* __restrict__ wtil, float* __restrict__ wT) {
  int blk = blockIdx.x;
  if (blk < 64) {
    int gid = blk * 256 + threadIdx.x;  // 16384 threads
    int n  = gid & 511;
    int kg = gid >> 9;
    bf16x8 hv, lv;
    float vv[8];
#pragma unroll
    for (int j = 0; j < 8; ++j) {
      float v = w[(kg * 8 + j) * 512 + n];
      vv[j] = v;
      unsigned h = bf16_rne(v);
      float hf = __uint_as_float(h << 16);
      unsigned l = bf16_rne(v - hf);
      hv[j] = (short)h;
      lv[j] = (short)l;
    }
    short* dst = wtil + (size_t)gid * 8;   // (kg*512 + n)*8
    *(bf16x8*)dst = hv;
    *(bf16x8*)(dst + 131072) = lv;
    if (wT) {
      float* p = wT + (size_t)n * 256 + kg * 8;
      *(float4*)p       = make_float4(vv[0], vv[1], vv[2], vv[3]);
      *(float4*)(p + 4) = make_float4(vv[4], vv[5], vv[6], vv[7]);
    }
  } else {
    int t = (blk - 64) * 256 + threadIdx.x;  // 0..2047
    int k = t >> 2;
    int part = t & 3;
    double s = 0.0;
#pragma unroll 8
    for (int d = part * 64; d < part * 64 + 64; ++d) {
      double v = (double)w[d * 512 + k];
      s = fma(v, v, s);
    }
    s += __shfl_xor(s, 1);
    s += __shfl_xor(s, 2);
    if (part == 0) e2[k] = (float)s;
  }
}

// ---------------------------------------------------------------------------
// vq_main: 256 blocks (1/CU), 1024 threads (16 waves, 4 waves/SIMD).
// Block = 128 positions x 512 codes; wave owns 32 codes x all 128 positions.
// Codebook L2 stream halved vs 64-pos blocks (256 x 512 KB = 128 MB total).
// Staging swizzle adds the (m>>3) term: writes at the 4-way b128 floor
// (was 16-way); K-loop reads stay conflict-free.
// ---------------------------------------------------------------------------
__global__ __launch_bounds__(1024, 4) void vq_main(
    const float* __restrict__ x, const float* __restrict__ w,
    const float* __restrict__ e2g, const short* __restrict__ wtil,
    const float* __restrict__ wT,
    float* __restrict__ out, float* __restrict__ arg_out) {
  __shared__ __align__(16) char arena[137216];
  short* xh   = (short*)arena;                 // [128][256] swizzled, 64 KB
  short* xl   = (short*)(arena + 65536);       // 64 KB
  float* e2s  = (float*)(arena + 131072);      // 2 KB
  // scan phase (xh dead after K-loop + sync): tv/ti alias xh
  float* tv1  = (float*)arena;                 // [16][128]
  float* tv2  = (float*)(arena + 8192);
  int*   ti1  = (int*)(arena + 16384);
  int*   ti2  = (int*)(arena + 24576);
  int*   p1S  = (int*)(arena + 135168);        // [128] — survives gather
  int*   p2S  = (int*)(arena + 135680);
  int*   needS= (int*)(arena + 136192);
  int*   rpickS=(int*)(arena + 136704);
  // gather phase: gbuf[d*132 + pos], 256x132 floats = 135168 B (all else dead)
  float* gbuf = (float*)arena;

  const int tid = threadIdx.x;
  const int b  = blockIdx.x >> 3;
  const int n0 = (blockIdx.x & 7) << 7;        // 128 positions
  const float* xbase = x + (size_t)b * 262144 + n0;

  // ---- stage all 256 dims (thread: 4 positions x 8 dims)
  {
    if (tid < 512) e2s[tid] = e2g[tid];
    const int n4  = tid & 31;      // position-quad (4 pos each)
    const int kgp = tid >> 5;      // 0..31: all kg groups
    float4 v[8];
#pragma unroll
    for (int j = 0; j < 8; ++j)
      v[j] = *(const float4*)(xbase + (size_t)(kgp * 8 + j) * 1024 + (n4 << 2));
#pragma unroll
    for (int i = 0; i < 4; ++i) {
      int m = (n4 << 2) + i;
      union { int w4[4]; bf16x8 v8; } H, L;
#pragma unroll
      for (int jj = 0; jj < 4; ++jj) {
        float a = (i == 0) ? v[2*jj].x : (i == 1) ? v[2*jj].y : (i == 2) ? v[2*jj].z : v[2*jj].w;
        float c = (i == 0) ? v[2*jj+1].x : (i == 1) ? v[2*jj+1].y : (i == 2) ? v[2*jj+1].z : v[2*jj+1].w;
        unsigned hu = pk_bf16(a, c);
        float haf = __uint_as_float(hu << 16);
        float hcf = __uint_as_float(hu & 0xffff0000u);
        unsigned lu = pk_bf16(a - haf, c - hcf);
        H.w4[jj] = (int)hu;
        L.w4[jj] = (int)lu;
      }
      int slot = kgp ^ (m & 7) ^ ((m >> 3) & 7);
      int off = (m << 8) + (slot << 3);
      *(bf16x8*)&xh[off] = H.v8;
      *(bf16x8*)&xl[off] = L.v8;
    }
  }
  __syncthreads();

  const int lane = tid & 63;
  const int wv   = tid >> 6;     // wave 0..15: codes [wv*32, wv*32+32)
  const int ln   = lane & 31;
  const int half = lane >> 5;
  const int wb   = wv << 5;

  f32x16 acc[4];   // [pos-tile pt], single 32-code tile per wave
#pragma unroll
  for (int pt = 0; pt < 4; ++pt)
#pragma unroll
    for (int r = 0; r < 16; ++r) acc[pt][r] = 0.f;

  const int sw0   = ((ln & 7) ^ (ln >> 3)) << 3;  // lane swizzle, short units
  const int abase = ln << 8;
  const int bofs  = (wb + ln) << 3;

  bf16x8 pch, pcl;
  {
    const short* p = wtil + (half << 12) + bofs;
    pch = *(const bf16x8*)p;
    pcl = *(const bf16x8*)(p + 131072);
  }

  auto kstep = [&](int ch) {
    const int kg = (ch << 1) + half;
    bf16x8 cfh = pch, cfl = pcl;
    if (ch < 15) {
      const short* p = wtil + ((((ch + 1) << 1) + half) << 12) + bofs;
      pch = *(const bf16x8*)p;
      pcl = *(const bf16x8*)(p + 131072);
    }
    const int kbase = (kg << 3) ^ sw0;
#pragma unroll
    for (int pt = 0; pt < 4; ++pt) {
      const int ao = abase + (pt << 13) + (kbase ^ ((pt & 1) << 5));
      bf16x8 xf = *(const bf16x8*)&xh[ao];
      bf16x8 xg = *(const bf16x8*)&xl[ao];
      acc[pt] = __builtin_amdgcn_mfma_f32_32x32x16_bf16(cfh, xf, acc[pt], 0, 0, 0);
      acc[pt] = __builtin_amdgcn_mfma_f32_32x32x16_bf16(cfh, xg, acc[pt], 0, 0, 0);
      acc[pt] = __builtin_amdgcn_mfma_f32_32x32x16_bf16(cfl, xf, acc[pt], 0, 0, 0);
    }
  };

  kstep(0);  kstep(1);  kstep(2);  kstep(3);
  kstep(4);  kstep(5);  kstep(6);  kstep(7);
  kstep(8);  kstep(9);  kstep(10); kstep(11);
  kstep(12); kstep(13); kstep(14); kstep(15);

  __syncthreads();   // xh/xl reads done; tv/ti alias becomes safe

  // ---- epilogue: per-lane register scan; e2 from LDS (lives at 131072)
#pragma unroll
  for (int pt = 0; pt < 4; ++pt) {
    float v1 = 3.4e38f, v2 = 3.4e38f;
    int i1 = 0x7fffffff, i2 = 0x7fffffff;
#pragma unroll
    for (int r = 0; r < 16; ++r) {
      int k = wb + (r & 3) + ((r >> 2) << 3) + (half << 2);
      float s = fmaf(-2.f, acc[pt][r], e2s[k]);
      if (lex_lt(s, k, v1, i1)) { v2 = v1; i2 = i1; v1 = s; i1 = k; }
      else if (lex_lt(s, k, v2, i2)) { v2 = s; i2 = k; }
    }
    {
      float ov1 = __shfl_xor(v1, 32);
      int   oi1 = __shfl_xor(i1, 32);
      float ov2 = __shfl_xor(v2, 32);
      int   oi2 = __shfl_xor(i2, 32);
      bool aFirst = lex_lt(v1, i1, ov1, oi1);
      float nv1 = aFirst ? v1 : ov1;  int ni1 = aFirst ? i1 : oi1;
      float cv  = aFirst ? ov1 : v1;  int ci  = aFirst ? oi1 : i1;
      float sv  = aFirst ? v2 : ov2;  int si  = aFirst ? i2 : oi2;
      bool cFirst = lex_lt(cv, ci, sv, si);
      v1 = nv1; i1 = ni1;
      v2 = cFirst ? cv : sv; i2 = cFirst ? ci : si;
    }
    if (half == 0) {
      int s = (wv << 7) + (pt << 5) + ln;
      tv1[s] = v1; ti1[s] = i1; tv2[s] = v2; ti2[s] = i2;
    }
  }
  __syncthreads();

  // ---- cross-wave merge (tid<128), publish top-2 + need flag
  if (tid < 128) {
    int row = tid;
    float v1 = 3.4e38f, v2 = 3.4e38f;
    int i1 = 0x7fffffff, i2 = 0x7fffffff;
#pragma unroll
    for (int wvv = 0; wvv < 16; ++wvv) {
      int s = (wvv << 7) + row;
      float a1 = tv1[s]; int ai = ti1[s];
      float a2 = tv2[s]; int bi = ti2[s];
      if (lex_lt(a1, ai, v1, i1)) { v2 = v1; i2 = i1; v1 = a1; i1 = ai; }
      else if (lex_lt(a1, ai, v2, i2)) { v2 = a1; i2 = ai; }
      if (lex_lt(a2, bi, v1, i1)) { v2 = v1; i2 = i1; v1 = a2; i1 = bi; }
      else if (lex_lt(a2, bi, v2, i2)) { v2 = a2; i2 = bi; }
    }
    p1S[row] = i1; p2S[row] = i2;
    needS[row] = (v2 - v1 < 0.01f) ? 1 : 0;   // >3x worst-case split-GEMM jitter
    rpickS[row] = i1;
  }
  __syncthreads();

  // ---- parallel fp64 refinement: wave wv handles rows wv, wv+16, ...
  for (int t = 0; t < 8; ++t) {
    int row = (t << 4) + wv;
    if (needS[row]) {
      int i1 = p1S[row], i2 = p2S[row];
      const float* xp = x + (size_t)b * 262144 + n0 + row;
      double s1 = 0.0, s2 = 0.0;
      int k0 = lane << 2;
#pragma unroll
      for (int i = 0; i < 4; ++i) {
        int k = k0 + i;
        double xv = (double)xp[(size_t)k * 1024];
        double w1 = (double)w[k * 512 + i1];
        double w2 = (double)w[k * 512 + i2];
        double t1 = xv - w1, t2 = xv - w2;
        s1 = fma(t1, t1, s1);
        s2 = fma(t2, t2, s2);
      }
#pragma unroll
      for (int off = 32; off >= 1; off >>= 1) {
        s1 += __shfl_xor(s1, off);
        s2 += __shfl_xor(s2, off);
      }
      if (lane == 0 && (s2 < s1 || (s2 == s1 && i2 < i1))) rpickS[row] = i2;
    }
  }
  __syncthreads();

  // ---- write argmin + gather via transposed LDS bounce
  if (tid < 128) arg_out[b * 1024 + n0 + tid] = (float)rpickS[tid];

  if (wT) {
    {
      const int pos  = tid >> 3;        // 128 positions, 8 threads each
      const int dseg = tid & 7;
      const float* wrow = wT + (size_t)rpickS[pos] * 256;
#pragma unroll
      for (int j = 0; j < 8; ++j) {
        int d0 = (j << 5) + (dseg << 2);
        float4 v = *(const float4*)(wrow + d0);
        gbuf[(d0 + 0) * 132 + pos] = v.x;
        gbuf[(d0 + 1) * 132 + pos] = v.y;
        gbuf[(d0 + 2) * 132 + pos] = v.z;
        gbuf[(d0 + 3) * 132 + pos] = v.w;
      }
    }
    __syncthreads();
    {
      const int nn0 = (tid & 31) << 2;
      const int d0g = tid >> 5;          // 0..31
      float* obase = out + (size_t)b * 262144 + n0 + nn0;
#pragma unroll
      for (int dg = 0; dg < 8; ++dg) {
        int d = d0g + (dg << 5);
        float4 o = *(const float4*)&gbuf[d * 132 + nn0];
        *(float4*)(obase + (size_t)d * 1024) = o;
      }
    }
  } else {
    const int nn0 = (tid & 31) << 2;
    const int d0g = tid >> 5;
    int pk0 = rpickS[nn0], pk1 = rpickS[nn0 + 1], pk2 = rpickS[nn0 + 2], pk3 = rpickS[nn0 + 3];
    float* obase = out + (size_t)b * 262144 + n0 + nn0;
#pragma unroll
    for (int dg = 0; dg < 8; ++dg) {
      int d = d0g + (dg << 5);
      const float* wr = w + d * 512;
      float4 o = make_float4(wr[pk0], wr[pk1], wr[pk2], wr[pk3]);
      *(float4*)(obase + (size_t)d * 1024) = o;
    }
  }
}

// ---------------------------------------------------------------------------
extern "C" void kernel_launch(void* const* d_in, const int* in_sizes, int n_in,
                              void* d_out, int out_size, void* d_ws, size_t ws_size,
                              hipStream_t stream) {
  const float* x = (const float*)d_in[0];
  const float* w = (const float*)d_in[1];
  float* out  = (float*)d_out;
  float* argf = out + 8388608;
  float* e2   = (float*)d_ws;                       // 2048 B
  short* wtil = (short*)((char*)d_ws + 2048);       // 512 KB
  size_t need = 2048 + 524288 + 524288;
  float* wT   = (ws_size >= need) ? (float*)((char*)d_ws + 2048 + 524288) : nullptr;

  vq_pre<<<72, 256, 0, stream>>>(w, e2, wtil, wT);
  vq_main<<<256, 1024, 0, stream>>>(x, w, e2, wtil, wT, out, argf);
}

// Round 7
// 117.034 us; speedup vs baseline: 1.6720x; 1.0247x over previous
//
#include <hip/hip_runtime.h>

typedef __attribute__((ext_vector_type(8))) short bf16x8;
typedef __attribute__((ext_vector_type(16))) float f32x16;

__device__ __forceinline__ bool lex_lt(float av, int ai, float bv, int bi) {
  return av < bv || (av == bv && ai < bi);
}

// round-to-nearest-even fp32 -> bf16 (low 16 bits)
__device__ __forceinline__ unsigned bf16_rne(float v) {
  unsigned u = __float_as_uint(v);
  return (u + 0x7fffu + ((u >> 16) & 1u)) >> 16;
}

// packed RNE bf16 convert of (a,b) -> one 32-bit word (low=a, high=b)
__device__ __forceinline__ unsigned pk_bf16(float a, float b) {
  return bf16_rne(a) | (bf16_rne(b) << 16);
}

// ---------------------------------------------------------------------------
// vq_pre: blocks 0..63 build k-major bf16-split codebook planes
// wh[kg][n][8], wl[kg][n][8] + exact fp32 transposed codebook wT[n][d];
// blocks 64..71: e2[k] in fp64 (4-way d-split per k).
// ---------------------------------------------------------------------------
__global__ __launch_bounds__(256) void vq_pre(
    const float* __restrict__ w, float* __restrict__ e2,
    short* __restrict__ wtil, float* __restrict__ wT) {
  int blk = blockIdx.x;
  if (blk < 64) {
    int gid = blk * 256 + threadIdx.x;  // 16384 threads
    int n  = gid & 511;
    int kg = gid >> 9;
    bf16x8 hv, lv;
    float vv[8];
#pragma unroll
    for (int j = 0; j < 8; ++j) {
      float v = w[(kg * 8 + j) * 512 + n];
      vv[j] = v;
      unsigned h = bf16_rne(v);
      float hf = __uint_as_float(h << 16);
      unsigned l = bf16_rne(v - hf);
      hv[j] = (short)h;
      lv[j] = (short)l;
    }
    short* dst = wtil + (size_t)gid * 8;   // (kg*512 + n)*8
    *(bf16x8*)dst = hv;
    *(bf16x8*)(dst + 131072) = lv;
    if (wT) {
      float* p = wT + (size_t)n * 256 + kg * 8;
      *(float4*)p       = make_float4(vv[0], vv[1], vv[2], vv[3]);
      *(float4*)(p + 4) = make_float4(vv[4], vv[5], vv[6], vv[7]);
    }
  } else {
    int t = (blk - 64) * 256 + threadIdx.x;  // 0..2047
    int k = t >> 2;
    int part = t & 3;
    double s = 0.0;
#pragma unroll 8
    for (int d = part * 64; d < part * 64 + 64; ++d) {
      double v = (double)w[d * 512 + k];
      s = fma(v, v, s);
    }
    s += __shfl_xor(s, 1);
    s += __shfl_xor(s, 2);
    if (part == 0) e2[k] = (float)s;
  }
}

// ---------------------------------------------------------------------------
// vq_main: 512 blocks (2/CU), 512 threads (8 waves).
// Block = 64 positions x 512 codes; wave owns 64 codes (ct=2, x-frag reuse).
// This round: (1) BOTH-side swizzle slot = kg ^ (m&7) ^ ((m>>3)&7) ->
// staging writes at the conflict-free b128 floor; (2) x-fragment prefetch
// depth-1 in the K-loop; (3) per-wave chunk stagger (wave wv starts at
// chunk (wv&7)*2, wraps mod 16) to de-phase MFMA/LDS/L2 usage across waves.
// ---------------------------------------------------------------------------
__global__ __launch_bounds__(512, 4) void vq_main(
    const float* __restrict__ x, const float* __restrict__ w,
    const float* __restrict__ e2g, const short* __restrict__ wtil,
    const float* __restrict__ wT,
    float* __restrict__ out, float* __restrict__ arg_out) {
  __shared__ __align__(16) char arena[76800];
  short* xh   = (short*)arena;                 // [64][256] swizzled, 32 KB
  short* xl   = (short*)(arena + 32768);       // 32 KB
  float* e2s  = (float*)(arena + 65536);       // 2 KB
  float* tv1  = (float*)(arena + 67584);       // [8][64]
  float* tv2  = (float*)(arena + 69632);
  int*   ti1  = (int*)(arena + 71680);
  int*   ti2  = (int*)(arena + 73728);
  int*   p1S  = (int*)(arena + 75776);         // [64]
  int*   p2S  = (int*)(arena + 76032);
  int*   needS= (int*)(arena + 76288);
  int*   rpickS=(int*)(arena + 76544);
  // gather phase: gbuf[d*68 + pos], 256x68 floats = 69632 B
  // (aliases xh/xl/e2s/tv which are dead; p1S..rpickS at >=75776 survive)
  float* gbuf = (float*)arena;

  const int tid = threadIdx.x;
  const int b  = blockIdx.x >> 4;
  const int n0 = (blockIdx.x & 15) << 6;       // 64 positions
  const float* xbase = x + (size_t)b * 262144 + n0;

  // ---- stage all 256 dims in one pass
  {
    e2s[tid] = e2g[tid];
    const int n4  = tid & 15;      // position-quad (4 pos each)
    const int kgp = tid >> 4;      // 0..31: all kg groups
    float4 v[8];
#pragma unroll
    for (int j = 0; j < 8; ++j)
      v[j] = *(const float4*)(xbase + (size_t)(kgp * 8 + j) * 1024 + (n4 << 2));
#pragma unroll
    for (int i = 0; i < 4; ++i) {
      int m = (n4 << 2) + i;
      union { int w4[4]; bf16x8 v8; } H, L;
#pragma unroll
      for (int jj = 0; jj < 4; ++jj) {
        float a = (i == 0) ? v[2*jj].x : (i == 1) ? v[2*jj].y : (i == 2) ? v[2*jj].z : v[2*jj].w;
        float c = (i == 0) ? v[2*jj+1].x : (i == 1) ? v[2*jj+1].y : (i == 2) ? v[2*jj+1].z : v[2*jj+1].w;
        unsigned hu = pk_bf16(a, c);
        float haf = __uint_as_float(hu << 16);
        float hcf = __uint_as_float(hu & 0xffff0000u);
        unsigned lu = pk_bf16(a - haf, c - hcf);
        H.w4[jj] = (int)hu;
        L.w4[jj] = (int)lu;
      }
      int slot = kgp ^ (m & 7) ^ ((m >> 3) & 7);
      int off = (m << 8) + (slot << 3);
      *(bf16x8*)&xh[off] = H.v8;
      *(bf16x8*)&xl[off] = L.v8;
    }
  }
  __syncthreads();

  const int lane = tid & 63;
  const int wv   = tid >> 6;     // wave 0..7: codes [wv*64, wv*64+64)
  const int ln   = lane & 31;
  const int half = lane >> 5;
  const int wb   = wv << 6;

  f32x16 acc[2][2];   // [code-tile ct][pos-tile pt]
#pragma unroll
  for (int ct = 0; ct < 2; ++ct)
#pragma unroll
    for (int pt = 0; pt < 2; ++pt)
#pragma unroll
      for (int r = 0; r < 16; ++r) acc[ct][pt][r] = 0.f;

  const int sw    = (ln & 7) ^ (ln >> 3);   // read swizzle (matches write)
  const int abase = ln << 8;

  int bofs[2];
#pragma unroll
  for (int ct = 0; ct < 2; ++ct) bofs[ct] = (wb + (ct << 5) + ln) << 3;

  // ---- K-loop: per-wave staggered chunk order, depth-1 prefetch of x-frags
  //      and code-frags. Chunk c_i = (st + i) & 15.
  const int st = (wv & 7) << 1;

  bf16x8 xf[2], xg[2], pch[2], pcl[2];
  {
    const int kg = (st << 1) + half;
    const int s0 = ((kg ^ sw) << 3);
    const int a0 = abase + s0;
    const int a1 = abase + 8192 + (s0 ^ 32);   // pt=1: slot ^= 4
    xf[0] = *(const bf16x8*)&xh[a0]; xg[0] = *(const bf16x8*)&xl[a0];
    xf[1] = *(const bf16x8*)&xh[a1]; xg[1] = *(const bf16x8*)&xl[a1];
    const short* p0 = wtil + (kg << 12) + bofs[0];
    const short* p1 = wtil + (kg << 12) + bofs[1];
    pch[0] = *(const bf16x8*)p0; pcl[0] = *(const bf16x8*)(p0 + 131072);
    pch[1] = *(const bf16x8*)p1; pcl[1] = *(const bf16x8*)(p1 + 131072);
  }

#pragma unroll
  for (int i = 0; i < 16; ++i) {
    bf16x8 cxf[2], cxg[2], cch[2], ccl[2];
#pragma unroll
    for (int q = 0; q < 2; ++q) {
      cxf[q] = xf[q]; cxg[q] = xg[q]; cch[q] = pch[q]; ccl[q] = pcl[q];
    }
    if (i < 15) {
      const int kgn = ((((st >> 1) + i + 1) & 15) << 2) + (half << 1)
                      - (((st >> 1) + i + 1) & 15) * 2;  // see below
      // simpler: chunk cn = (st/2 + i + 1) & 15 is wrong — st is already the
      // chunk index. Compute directly:
      const int cn  = (st + i + 1) & 15;
      const int kg2 = (cn << 1) + half;
      const int s0  = ((kg2 ^ sw) << 3);
      const int a0  = abase + s0;
      const int a1  = abase + 8192 + (s0 ^ 32);
      xf[0] = *(const bf16x8*)&xh[a0]; xg[0] = *(const bf16x8*)&xl[a0];
      xf[1] = *(const bf16x8*)&xh[a1]; xg[1] = *(const bf16x8*)&xl[a1];
      const short* p0 = wtil + (kg2 << 12) + bofs[0];
      const short* p1 = wtil + (kg2 << 12) + bofs[1];
      pch[0] = *(const bf16x8*)p0; pcl[0] = *(const bf16x8*)(p0 + 131072);
      pch[1] = *(const bf16x8*)p1; pcl[1] = *(const bf16x8*)(p1 + 131072);
      (void)kgn;
    }
#pragma unroll
    for (int ct = 0; ct < 2; ++ct)
#pragma unroll
      for (int pt = 0; pt < 2; ++pt) {
        acc[ct][pt] = __builtin_amdgcn_mfma_f32_32x32x16_bf16(cch[ct], cxf[pt], acc[ct][pt], 0, 0, 0);
        acc[ct][pt] = __builtin_amdgcn_mfma_f32_32x32x16_bf16(cch[ct], cxg[pt], acc[ct][pt], 0, 0, 0);
        acc[ct][pt] = __builtin_amdgcn_mfma_f32_32x32x16_bf16(ccl[ct], cxf[pt], acc[ct][pt], 0, 0, 0);
      }
  }

  // ---- epilogue: per-lane register scan (codes in regs), one xor-32 merge
  float e2r[2][16];
#pragma unroll
  for (int ct = 0; ct < 2; ++ct)
#pragma unroll
    for (int r = 0; r < 16; ++r)
      e2r[ct][r] = e2s[wb + (ct << 5) + (r & 3) + ((r >> 2) << 3) + (half << 2)];

#pragma unroll
  for (int pt = 0; pt < 2; ++pt) {
    float v1 = 3.4e38f, v2 = 3.4e38f;
    int i1 = 0x7fffffff, i2 = 0x7fffffff;
#pragma unroll
    for (int ct = 0; ct < 2; ++ct) {
#pragma unroll
      for (int r = 0; r < 16; ++r) {
        int k = wb + (ct << 5) + (r & 3) + ((r >> 2) << 3) + (half << 2);
        float s = fmaf(-2.f, acc[ct][pt][r], e2r[ct][r]);
        if (lex_lt(s, k, v1, i1)) { v2 = v1; i2 = i1; v1 = s; i1 = k; }
        else if (lex_lt(s, k, v2, i2)) { v2 = s; i2 = k; }
      }
    }
    {
      float ov1 = __shfl_xor(v1, 32);
      int   oi1 = __shfl_xor(i1, 32);
      float ov2 = __shfl_xor(v2, 32);
      int   oi2 = __shfl_xor(i2, 32);
      bool aFirst = lex_lt(v1, i1, ov1, oi1);
      float nv1 = aFirst ? v1 : ov1;  int ni1 = aFirst ? i1 : oi1;
      float cv  = aFirst ? ov1 : v1;  int ci  = aFirst ? oi1 : i1;
      float sv  = aFirst ? v2 : ov2;  int si  = aFirst ? i2 : oi2;
      bool cFirst = lex_lt(cv, ci, sv, si);
      v1 = nv1; i1 = ni1;
      v2 = cFirst ? cv : sv; i2 = cFirst ? ci : si;
    }
    if (half == 0) {
      int s = (wv << 6) + (pt << 5) + ln;
      tv1[s] = v1; ti1[s] = i1; tv2[s] = v2; ti2[s] = i2;
    }
  }
  __syncthreads();

  // ---- cross-wave merge (tid<64), publish top-2 + need flag
  if (tid < 64) {
    int row = tid;
    float v1 = 3.4e38f, v2 = 3.4e38f;
    int i1 = 0x7fffffff, i2 = 0x7fffffff;
#pragma unroll
    for (int wvv = 0; wvv < 8; ++wvv) {
      int s = (wvv << 6) + row;
      float a1 = tv1[s]; int ai = ti1[s];
      float a2 = tv2[s]; int bi = ti2[s];
      if (lex_lt(a1, ai, v1, i1)) { v2 = v1; i2 = i1; v1 = a1; i1 = ai; }
      else if (lex_lt(a1, ai, v2, i2)) { v2 = a1; i2 = ai; }
      if (lex_lt(a2, bi, v1, i1)) { v2 = v1; i2 = i1; v1 = a2; i1 = bi; }
      else if (lex_lt(a2, bi, v2, i2)) { v2 = a2; i2 = bi; }
    }
    p1S[row] = i1; p2S[row] = i2;
    needS[row] = (v2 - v1 < 0.01f) ? 1 : 0;   // >3x worst-case split-GEMM jitter
    rpickS[row] = i1;
  }
  __syncthreads();

  // ---- parallel fp64 refinement: wave wv handles rows wv, wv+8, ...
  for (int t = 0; t < 8; ++t) {
    int row = (t << 3) + wv;
    if (needS[row]) {
      int i1 = p1S[row], i2 = p2S[row];
      const float* xp = x + (size_t)b * 262144 + n0 + row;
      double s1 = 0.0, s2 = 0.0;
      int k0 = lane << 2;
#pragma unroll
      for (int i = 0; i < 4; ++i) {
        int k = k0 + i;
        double xv = (double)xp[(size_t)k * 1024];
        double w1 = (double)w[k * 512 + i1];
        double w2 = (double)w[k * 512 + i2];
        double t1 = xv - w1, t2 = xv - w2;
        s1 = fma(t1, t1, s1);
        s2 = fma(t2, t2, s2);
      }
#pragma unroll
      for (int off = 32; off >= 1; off >>= 1) {
        s1 += __shfl_xor(s1, off);
        s2 += __shfl_xor(s2, off);
      }
      if (lane == 0 && (s2 < s1 || (s2 == s1 && i2 < i1))) rpickS[row] = i2;
    }
  }
  __syncthreads();

  // ---- write argmin + gather via transposed LDS bounce
  if (tid < 64) arg_out[b * 1024 + n0 + tid] = (float)rpickS[tid];

  if (wT) {
    {
      const int pos  = tid >> 3;        // 64 positions, 8 threads each
      const int dseg = tid & 7;
      const float* wrow = wT + (size_t)rpickS[pos] * 256;
#pragma unroll
      for (int j = 0; j < 8; ++j) {
        int d0 = (j << 5) + (dseg << 2);
        float4 v = *(const float4*)(wrow + d0);
        gbuf[(d0 + 0) * 68 + pos] = v.x;
        gbuf[(d0 + 1) * 68 + pos] = v.y;
        gbuf[(d0 + 2) * 68 + pos] = v.z;
        gbuf[(d0 + 3) * 68 + pos] = v.w;
      }
    }
    __syncthreads();
    {
      const int nn0 = (tid & 15) << 2;
      const int d0g = tid >> 4;          // 0..31
      float* obase = out + (size_t)b * 262144 + n0 + nn0;
#pragma unroll
      for (int dg = 0; dg < 8; ++dg) {
        int d = d0g + (dg << 5);
        float4 o = *(const float4*)&gbuf[d * 68 + nn0];
        *(float4*)(obase + (size_t)d * 1024) = o;
      }
    }
  } else {
    const int nn0 = (tid & 15) << 2;
    const int d0g = tid >> 4;
    int pk0 = rpickS[nn0], pk1 = rpickS[nn0 + 1], pk2 = rpickS[nn0 + 2], pk3 = rpickS[nn0 + 3];
    float* obase = out + (size_t)b * 262144 + n0 + nn0;
#pragma unroll
    for (int dg = 0; dg < 8; ++dg) {
      int d = d0g + (dg << 5);
      const float* wr = w + d * 512;
      float4 o = make_float4(wr[pk0], wr[pk1], wr[pk2], wr[pk3]);
      *(float4*)(obase + (size_t)d * 1024) = o;
    }
  }
}

// ---------------------------------------------------------------------------
extern "C" void kernel_launch(void* const* d_in, const int* in_sizes, int n_in,
                              void* d_out, int out_size, void* d_ws, size_t ws_size,
                              hipStream_t stream) {
  const float* x = (const float*)d_in[0];
  const float* w = (const float*)d_in[1];
  float* out  = (float*)d_out;
  float* argf = out + 8388608;
  float* e2   = (float*)d_ws;                       // 2048 B
  short* wtil = (short*)((char*)d_ws + 2048);       // 512 KB
  size_t need = 2048 + 524288 + 524288;
  float* wT   = (ws_size >= need) ? (float*)((char*)d_ws + 2048 + 524288) : nullptr;

  vq_pre<<<72, 256, 0, stream>>>(w, e2, wtil, wT);
  vq_main<<<512, 512, 0, stream>>>(x, w, e2, wtil, wT, out, argf);
}

// Round 8
// 115.247 us; speedup vs baseline: 1.6980x; 1.0155x over previous
//
#include <hip/hip_runtime.h>

typedef __attribute__((ext_vector_type(8))) short bf16x8;
typedef __attribute__((ext_vector_type(16))) float f32x16;

__device__ __forceinline__ bool lex_lt(float av, int ai, float bv, int bi) {
  return av < bv || (av == bv && ai < bi);
}

// round-to-nearest-even fp32 -> bf16 (low 16 bits)
__device__ __forceinline__ unsigned bf16_rne(float v) {
  unsigned u = __float_as_uint(v);
  return (u + 0x7fffu + ((u >> 16) & 1u)) >> 16;
}

// packed RNE bf16 convert of (a,b) -> one 32-bit word (low=a, high=b)
__device__ __forceinline__ unsigned pk_bf16(float a, float b) {
  return bf16_rne(a) | (bf16_rne(b) << 16);
}

// ---------------------------------------------------------------------------
// vq_pre: blocks 0..63 build k-major bf16-split codebook planes
// wh[kg][n][8], wl[kg][n][8] + exact fp32 transposed codebook wT[n][d];
// blocks 64..71: e2[k] in fp64 (4-way d-split per k).
// ---------------------------------------------------------------------------
__global__ __launch_bounds__(256) void vq_pre(
    const float* __restrict__ w, float* __restrict__ e2,
    short* __restrict__ wtil, float* __restrict__ wT) {
  int blk = blockIdx.x;
  if (blk < 64) {
    int gid = blk * 256 + threadIdx.x;  // 16384 threads
    int n  = gid & 511;
    int kg = gid >> 9;
    bf16x8 hv, lv;
    float vv[8];
#pragma unroll
    for (int j = 0; j < 8; ++j) {
      float v = w[(kg * 8 + j) * 512 + n];
      vv[j] = v;
      unsigned h = bf16_rne(v);
      float hf = __uint_as_float(h << 16);
      unsigned l = bf16_rne(v - hf);
      hv[j] = (short)h;
      lv[j] = (short)l;
    }
    short* dst = wtil + (size_t)gid * 8;   // (kg*512 + n)*8
    *(bf16x8*)dst = hv;
    *(bf16x8*)(dst + 131072) = lv;
    if (wT) {
      float* p = wT + (size_t)n * 256 + kg * 8;
      *(float4*)p       = make_float4(vv[0], vv[1], vv[2], vv[3]);
      *(float4*)(p + 4) = make_float4(vv[4], vv[5], vv[6], vv[7]);
    }
  } else {
    int t = (blk - 64) * 256 + threadIdx.x;  // 0..2047
    int k = t >> 2;
    int part = t & 3;
    double s = 0.0;
#pragma unroll 8
    for (int d = part * 64; d < part * 64 + 64; ++d) {
      double v = (double)w[d * 512 + k];
      s = fma(v, v, s);
    }
    s += __shfl_xor(s, 1);
    s += __shfl_xor(s, 2);
    if (part == 0) e2[k] = (float)s;
  }
}

// ---------------------------------------------------------------------------
// vq_main: 512 blocks (2/CU), 512 threads (8 waves).
// Block = 64 positions x 512 codes; wave owns 64 codes (ct=2, x-frag reuse).
// Lockstep chunk order (deliberate: one chunk's 32 KB wtil slice is exactly
// L1-sized; all waves streaming the same chunk keeps it L1-resident — the
// R7 stagger experiment proved de-phasing costs ~20 µs via L1 thrash).
// Both-sides LDS swizzle: write slot = kgp ^ (m&7) ^ ((m>>3)&7), read
// asw = (ln&7) ^ (ln>>3) with pt=1 ^32 — staging writes at the b128 floor.
// ---------------------------------------------------------------------------
__global__ __launch_bounds__(512, 4) void vq_main(
    const float* __restrict__ x, const float* __restrict__ w,
    const float* __restrict__ e2g, const short* __restrict__ wtil,
    const float* __restrict__ wT,
    float* __restrict__ out, float* __restrict__ arg_out) {
  __shared__ __align__(16) char arena[76800];
  short* xh   = (short*)arena;                 // [64][256] swizzled, 32 KB
  short* xl   = (short*)(arena + 32768);       // 32 KB
  float* e2s  = (float*)(arena + 65536);       // 2 KB
  float* tv1  = (float*)(arena + 67584);       // [8][64]
  float* tv2  = (float*)(arena + 69632);
  int*   ti1  = (int*)(arena + 71680);
  int*   ti2  = (int*)(arena + 73728);
  int*   p1S  = (int*)(arena + 75776);         // [64]
  int*   p2S  = (int*)(arena + 76032);
  int*   needS= (int*)(arena + 76288);
  int*   rpickS=(int*)(arena + 76544);
  // gather phase: gbuf[d*68 + pos], 256x68 floats = 69632 B
  // (aliases xh/xl/e2s/tv which are dead; p1S..rpickS at >=75776 survive)
  float* gbuf = (float*)arena;

  const int tid = threadIdx.x;
  const int b  = blockIdx.x >> 4;
  const int n0 = (blockIdx.x & 15) << 6;       // 64 positions
  const float* xbase = x + (size_t)b * 262144 + n0;

  // ---- stage all 256 dims in one pass
  {
    e2s[tid] = e2g[tid];
    const int n4  = tid & 15;      // position-quad (4 pos each)
    const int kgp = tid >> 4;      // 0..31: all kg groups
    float4 v[8];
#pragma unroll
    for (int j = 0; j < 8; ++j)
      v[j] = *(const float4*)(xbase + (size_t)(kgp * 8 + j) * 1024 + (n4 << 2));
#pragma unroll
    for (int i = 0; i < 4; ++i) {
      int m = (n4 << 2) + i;
      union { int w4[4]; bf16x8 v8; } H, L;
#pragma unroll
      for (int jj = 0; jj < 4; ++jj) {
        float a = (i == 0) ? v[2*jj].x : (i == 1) ? v[2*jj].y : (i == 2) ? v[2*jj].z : v[2*jj].w;
        float c = (i == 0) ? v[2*jj+1].x : (i == 1) ? v[2*jj+1].y : (i == 2) ? v[2*jj+1].z : v[2*jj+1].w;
        unsigned hu = pk_bf16(a, c);
        float haf = __uint_as_float(hu << 16);
        float hcf = __uint_as_float(hu & 0xffff0000u);
        unsigned lu = pk_bf16(a - haf, c - hcf);
        H.w4[jj] = (int)hu;
        L.w4[jj] = (int)lu;
      }
      int slot = kgp ^ (m & 7) ^ ((m >> 3) & 7);
      int off = (m << 8) + (slot << 3);
      *(bf16x8*)&xh[off] = H.v8;
      *(bf16x8*)&xl[off] = L.v8;
    }
  }
  __syncthreads();

  const int lane = tid & 63;
  const int wv   = tid >> 6;     // wave 0..7: codes [wv*64, wv*64+64)
  const int ln   = lane & 31;
  const int half = lane >> 5;
  const int wb   = wv << 6;

  f32x16 acc[2][2];   // [code-tile ct][pos-tile pt]
#pragma unroll
  for (int ct = 0; ct < 2; ++ct)
#pragma unroll
    for (int pt = 0; pt < 2; ++pt)
#pragma unroll
      for (int r = 0; r < 16; ++r) acc[ct][pt][r] = 0.f;

  const int asw = (ln & 7) ^ (ln >> 3);   // read swizzle (matches write)
  const int abase = ln << 8;

  int bofs[2];
#pragma unroll
  for (int ct = 0; ct < 2; ++ct) bofs[ct] = (wb + (ct << 5) + ln) << 3;

  bf16x8 pch[2], pcl[2];
#pragma unroll
  for (int ct = 0; ct < 2; ++ct) {
    const short* p = wtil + (half << 12) + bofs[ct];
    pch[ct] = *(const bf16x8*)p;
    pcl[ct] = *(const bf16x8*)(p + 131072);
  }

  auto kstep = [&](int ch) {
    const int kg = (ch << 1) + half;
    const int ao = abase + ((kg ^ asw) << 3);
    bf16x8 xf[2], xg[2];
#pragma unroll
    for (int pt = 0; pt < 2; ++pt) {
      const int ap = (ao + (pt << 13)) ^ (pt << 5);  // pos+32 flips slot bit 2
      xf[pt] = *(const bf16x8*)&xh[ap];
      xg[pt] = *(const bf16x8*)&xl[ap];
    }
    bf16x8 cfh[2], cfl[2];
#pragma unroll
    for (int ct = 0; ct < 2; ++ct) { cfh[ct] = pch[ct]; cfl[ct] = pcl[ct]; }
    if (ch < 15) {
      const int kgn = ((ch + 1) << 1) + half;
#pragma unroll
      for (int ct = 0; ct < 2; ++ct) {
        const short* p = wtil + (kgn << 12) + bofs[ct];
        pch[ct] = *(const bf16x8*)p;
        pcl[ct] = *(const bf16x8*)(p + 131072);
      }
    }
#pragma unroll
    for (int ct = 0; ct < 2; ++ct)
#pragma unroll
      for (int pt = 0; pt < 2; ++pt) {
        acc[ct][pt] = __builtin_amdgcn_mfma_f32_32x32x16_bf16(cfh[ct], xf[pt], acc[ct][pt], 0, 0, 0);
        acc[ct][pt] = __builtin_amdgcn_mfma_f32_32x32x16_bf16(cfh[ct], xg[pt], acc[ct][pt], 0, 0, 0);
        acc[ct][pt] = __builtin_amdgcn_mfma_f32_32x32x16_bf16(cfl[ct], xf[pt], acc[ct][pt], 0, 0, 0);
      }
  };

  kstep(0);  kstep(1);  kstep(2);  kstep(3);
  kstep(4);  kstep(5);  kstep(6);  kstep(7);
  kstep(8);  kstep(9);  kstep(10); kstep(11);
  kstep(12); kstep(13); kstep(14); kstep(15);

  // ---- epilogue: per-lane register scan (codes in regs), one xor-32 merge
  float e2r[2][16];
#pragma unroll
  for (int ct = 0; ct < 2; ++ct)
#pragma unroll
    for (int r = 0; r < 16; ++r)
      e2r[ct][r] = e2s[wb + (ct << 5) + (r & 3) + ((r >> 2) << 3) + (half << 2)];

#pragma unroll
  for (int pt = 0; pt < 2; ++pt) {
    float v1 = 3.4e38f, v2 = 3.4e38f;
    int i1 = 0x7fffffff, i2 = 0x7fffffff;
#pragma unroll
    for (int ct = 0; ct < 2; ++ct) {
#pragma unroll
      for (int r = 0; r < 16; ++r) {
        int k = wb + (ct << 5) + (r & 3) + ((r >> 2) << 3) + (half << 2);
        float s = fmaf(-2.f, acc[ct][pt][r], e2r[ct][r]);
        if (lex_lt(s, k, v1, i1)) { v2 = v1; i2 = i1; v1 = s; i1 = k; }
        else if (lex_lt(s, k, v2, i2)) { v2 = s; i2 = k; }
      }
    }
    {
      float ov1 = __shfl_xor(v1, 32);
      int   oi1 = __shfl_xor(i1, 32);
      float ov2 = __shfl_xor(v2, 32);
      int   oi2 = __shfl_xor(i2, 32);
      bool aFirst = lex_lt(v1, i1, ov1, oi1);
      float nv1 = aFirst ? v1 : ov1;  int ni1 = aFirst ? i1 : oi1;
      float cv  = aFirst ? ov1 : v1;  int ci  = aFirst ? oi1 : i1;
      float sv  = aFirst ? v2 : ov2;  int si  = aFirst ? i2 : oi2;
      bool cFirst = lex_lt(cv, ci, sv, si);
      v1 = nv1; i1 = ni1;
      v2 = cFirst ? cv : sv; i2 = cFirst ? ci : si;
    }
    if (half == 0) {
      int s = (wv << 6) + (pt << 5) + ln;
      tv1[s] = v1; ti1[s] = i1; tv2[s] = v2; ti2[s] = i2;
    }
  }
  __syncthreads();

  // ---- cross-wave merge (tid<64), publish top-2 + need flag
  if (tid < 64) {
    int row = tid;
    float v1 = 3.4e38f, v2 = 3.4e38f;
    int i1 = 0x7fffffff, i2 = 0x7fffffff;
#pragma unroll
    for (int wvv = 0; wvv < 8; ++wvv) {
      int s = (wvv << 6) + row;
      float a1 = tv1[s]; int ai = ti1[s];
      float a2 = tv2[s]; int bi = ti2[s];
      if (lex_lt(a1, ai, v1, i1)) { v2 = v1; i2 = i1; v1 = a1; i1 = ai; }
      else if (lex_lt(a1, ai, v2, i2)) { v2 = a1; i2 = ai; }
      if (lex_lt(a2, bi, v1, i1)) { v2 = v1; i2 = i1; v1 = a2; i1 = bi; }
      else if (lex_lt(a2, bi, v2, i2)) { v2 = a2; i2 = bi; }
    }
    p1S[row] = i1; p2S[row] = i2;
    needS[row] = (v2 - v1 < 0.01f) ? 1 : 0;   // >3x worst-case split-GEMM jitter
    rpickS[row] = i1;
  }
  __syncthreads();

  // ---- parallel fp64 refinement: wave wv handles rows wv, wv+8, ...
  for (int t = 0; t < 8; ++t) {
    int row = (t << 3) + wv;
    if (needS[row]) {
      int i1 = p1S[row], i2 = p2S[row];
      const float* xp = x + (size_t)b * 262144 + n0 + row;
      double s1 = 0.0, s2 = 0.0;
      int k0 = lane << 2;
#pragma unroll
      for (int i = 0; i < 4; ++i) {
        int k = k0 + i;
        double xv = (double)xp[(size_t)k * 1024];
        double w1 = (double)w[k * 512 + i1];
        double w2 = (double)w[k * 512 + i2];
        double t1 = xv - w1, t2 = xv - w2;
        s1 = fma(t1, t1, s1);
        s2 = fma(t2, t2, s2);
      }
#pragma unroll
      for (int off = 32; off >= 1; off >>= 1) {
        s1 += __shfl_xor(s1, off);
        s2 += __shfl_xor(s2, off);
      }
      if (lane == 0 && (s2 < s1 || (s2 == s1 && i2 < i1))) rpickS[row] = i2;
    }
  }
  __syncthreads();

  // ---- write argmin + gather via transposed LDS bounce
  if (tid < 64) arg_out[b * 1024 + n0 + tid] = (float)rpickS[tid];

  if (wT) {
    {
      const int pos  = tid >> 3;        // 64 positions, 8 threads each
      const int dseg = tid & 7;
      const float* wrow = wT + (size_t)rpickS[pos] * 256;
#pragma unroll
      for (int j = 0; j < 8; ++j) {
        int d0 = (j << 5) + (dseg << 2);
        float4 v = *(const float4*)(wrow + d0);
        gbuf[(d0 + 0) * 68 + pos] = v.x;
        gbuf[(d0 + 1) * 68 + pos] = v.y;
        gbuf[(d0 + 2) * 68 + pos] = v.z;
        gbuf[(d0 + 3) * 68 + pos] = v.w;
      }
    }
    __syncthreads();
    {
      const int nn0 = (tid & 15) << 2;
      const int d0g = tid >> 4;          // 0..31
      float* obase = out + (size_t)b * 262144 + n0 + nn0;
#pragma unroll
      for (int dg = 0; dg < 8; ++dg) {
        int d = d0g + (dg << 5);
        float4 o = *(const float4*)&gbuf[d * 68 + nn0];
        *(float4*)(obase + (size_t)d * 1024) = o;
      }
    }
  } else {
    const int nn0 = (tid & 15) << 2;
    const int d0g = tid >> 4;
    int pk0 = rpickS[nn0], pk1 = rpickS[nn0 + 1], pk2 = rpickS[nn0 + 2], pk3 = rpickS[nn0 + 3];
    float* obase = out + (size_t)b * 262144 + n0 + nn0;
#pragma unroll
    for (int dg = 0; dg < 8; ++dg) {
      int d = d0g + (dg << 5);
      const float* wr = w + d * 512;
      float4 o = make_float4(wr[pk0], wr[pk1], wr[pk2], wr[pk3]);
      *(float4*)(obase + (size_t)d * 1024) = o;
    }
  }
}

// ---------------------------------------------------------------------------
extern "C" void kernel_launch(void* const* d_in, const int* in_sizes, int n_in,
                              void* d_out, int out_size, void* d_ws, size_t ws_size,
                              hipStream_t stream) {
  const float* x = (const float*)d_in[0];
  const float* w = (const float*)d_in[1];
  float* out  = (float*)d_out;
  float* argf = out + 8388608;
  float* e2   = (float*)d_ws;                       // 2048 B
  short* wtil = (short*)((char*)d_ws + 2048);       // 512 KB
  size_t need = 2048 + 524288 + 524288;
  float* wT   = (ws_size >= need) ? (float*)((char*)d_ws + 2048 + 524288) : nullptr;

  vq_pre<<<72, 256, 0, stream>>>(w, e2, wtil, wT);
  vq_main<<<512, 512, 0, stream>>>(x, w, e2, wtil, wT, out, argf);
}